// Round 7
// baseline (258.913 us; speedup 1.0000x reference)
//
#include <hip/hip_runtime.h>
#include <hip/hip_bf16.h>

// LengthRegulator, round 7: R6 kernel UNCHANGED, launched TWICE (idempotent)
// as a timing probe — dur_us delta vs R6 == true kernel time T, which the
// rocprof top-5 (all harness poison-fills) has hidden for five rounds.
//   R6 structure: scatter-built window table in LDS, fill-identical pure-store
//   path for fully-pad blocks, plain (non-nt) dwordx4 stores, static
//   24-iteration unrolled copy, incremental f/c.
// Roofline: 192 MiB write + ~27 MiB read -> ~35 us at fill-rate 6.5 TB/s.

#define B    32
#define T    512
#define D    384
#define TOUT 4096           // T * DUR_MAX
#define CH   (D / 4)        // 96 float4 chunks per frame
#define F    128            // output frames per block
#define NT   512            // threads per block
#define ITEMS (F * CH)      // 12288 float4 per block
#define ITER (ITEMS / NT)   // 24

typedef float f4 __attribute__((ext_vector_type(4)));

__global__ __launch_bounds__(NT) void k_lenreg(const f4* __restrict__ xs4,
                                               const int* __restrict__ dur,
                                               f4* __restrict__ out4) {
    __shared__ int s_idx[F];        // frame->phoneme for this window, -1 = pad
    __shared__ int s_wsum[NT / 64];
    const int b      = blockIdx.y;
    const int frame0 = blockIdx.x * F;
    const int tid    = threadIdx.x;
    const int lane   = tid & 63;
    const int w      = tid >> 6;

    // ---- inclusive scan of this row's durations: shfl in wave, LDS combine ----
    int d = dur[b * T + tid];
    int sum = d;
    #pragma unroll
    for (int off = 1; off < 64; off <<= 1) {
        int v = __shfl_up(sum, off);
        if (lane >= off) sum += v;
    }
    if (lane == 63) s_wsum[w] = sum;
    __syncthreads();
    int prefix = 0, rowtot = 0;
    #pragma unroll
    for (int i = 0; i < NT / 64; ++i) {
        int v = s_wsum[i];
        rowtot += v;
        if (i < w) prefix += v;
    }
    int cum = sum + prefix;         // inclusive frame offset of phoneme tid

    // ---- torch edge case: row total 0 -> if GLOBAL total 0, all d become 1 ----
    if (rowtot == 0) {              // block-uniform, rare
        int g = 0;
        for (int i = tid; i < B * T; i += NT) g += dur[i];
        #pragma unroll
        for (int o = 32; o > 0; o >>= 1) g += __shfl_down(g, o);
        __syncthreads();
        if (lane == 0) s_wsum[w] = g;
        __syncthreads();
        int tot = 0;
        #pragma unroll
        for (int i = 0; i < NT / 64; ++i) tot += s_wsum[i];
        if (tot == 0) { d = 1; cum = tid + 1; rowtot = T; }
    }

    const size_t obase = ((size_t)b * TOUT + frame0) * CH;

    // ---- fully-pad window: fill-identical pure-store loop ----
    if (frame0 >= rowtot) {         // block-uniform
        const f4 z = (f4){0.f, 0.f, 0.f, 0.f};
        #pragma unroll
        for (int k = 0; k < ITER; ++k)
            out4[obase + tid + k * NT] = z;
        return;
    }

    // ---- scatter: phoneme tid owns frames [cum-d, cum) ∩ window ----
    if (tid < F) s_idx[tid] = -1;
    __syncthreads();
    {
        int a = cum - d, e = cum;
        if (a < frame0) a = frame0;
        int hi = frame0 + F;
        if (e > hi) e = hi;
        for (int k = a; k < e; ++k) s_idx[k - frame0] = tid;
    }
    __syncthreads();

    // ---- copy: static trip count, contiguous stores, incremental f/c ----
    const size_t ibase = (size_t)b * T * CH;
    int f = tid / CH;               // 0..5 (one div, outside loop)
    int c = tid - f * CH;
    #pragma unroll
    for (int k = 0; k < ITER; ++k) {
        int j = s_idx[f];           // <=2 distinct LDS addrs per wave
        f4 v = (f4){0.f, 0.f, 0.f, 0.f};
        if (j >= 0) v = xs4[ibase + (size_t)j * CH + c];
        out4[obase + tid + k * NT] = v;
        f += NT / CH;               // 512 = 5*96 + 32
        c += NT - (NT / CH) * CH;
        if (c >= CH) { c -= CH; ++f; }   // cndmask under unrolling
    }
}

extern "C" void kernel_launch(void* const* d_in, const int* in_sizes, int n_in,
                              void* d_out, int out_size, void* d_ws, size_t ws_size,
                              hipStream_t stream) {
    const float* xs  = (const float*)d_in[0];
    const int*   dur = (const int*)d_in[1];
    float*       out = (float*)d_out;

    dim3 grid(TOUT / F, B);         // 32 x 32 = 1024 blocks
    // PROBE: identical kernel twice (idempotent). dur_us - R6_dur == kernel T.
    k_lenreg<<<grid, NT, 0, stream>>>((const f4*)xs, dur, (f4*)out);
    k_lenreg<<<grid, NT, 0, stream>>>((const f4*)xs, dur, (f4*)out);
}

// Round 8
// 226.581 us; speedup vs baseline: 1.1427x; 1.1427x over previous
//
#include <hip/hip_runtime.h>
#include <hip/hip_bf16.h>

// LengthRegulator, round 8: R6 kernel, single launch (probe reverted).
// R7 double-launch probe measured true kernel time T ~= 31 us, vs a 201 MB
// mandatory-output-write roofline of ~30 us at the session's demonstrated
// 6.7 TB/s fill rate -> kernel is at ~97% of the achievable BW ceiling.
// Measured total (~228 us) is dominated by harness reset floor (~197 us:
// 768 MiB ws poison + 192 MiB out poison + input restore), invisible to
// kernel changes — which is why R2..R6 structural variants were all neutral.
//   Structure: shfl scan + scatter-built window table in LDS, fill-identical
//   pure-store path for fully-pad blocks (~56% of output), plain dwordx4
//   stores, static 24-iteration unrolled copy, incremental f/c (no div).

#define B    32
#define T    512
#define D    384
#define TOUT 4096           // T * DUR_MAX
#define CH   (D / 4)        // 96 float4 chunks per frame
#define F    128            // output frames per block
#define NT   512            // threads per block
#define ITEMS (F * CH)      // 12288 float4 per block
#define ITER (ITEMS / NT)   // 24

typedef float f4 __attribute__((ext_vector_type(4)));

__global__ __launch_bounds__(NT) void k_lenreg(const f4* __restrict__ xs4,
                                               const int* __restrict__ dur,
                                               f4* __restrict__ out4) {
    __shared__ int s_idx[F];        // frame->phoneme for this window, -1 = pad
    __shared__ int s_wsum[NT / 64];
    const int b      = blockIdx.y;
    const int frame0 = blockIdx.x * F;
    const int tid    = threadIdx.x;
    const int lane   = tid & 63;
    const int w      = tid >> 6;

    // ---- inclusive scan of this row's durations: shfl in wave, LDS combine ----
    int d = dur[b * T + tid];
    int sum = d;
    #pragma unroll
    for (int off = 1; off < 64; off <<= 1) {
        int v = __shfl_up(sum, off);
        if (lane >= off) sum += v;
    }
    if (lane == 63) s_wsum[w] = sum;
    __syncthreads();
    int prefix = 0, rowtot = 0;
    #pragma unroll
    for (int i = 0; i < NT / 64; ++i) {
        int v = s_wsum[i];
        rowtot += v;
        if (i < w) prefix += v;
    }
    int cum = sum + prefix;         // inclusive frame offset of phoneme tid

    // ---- torch edge case: row total 0 -> if GLOBAL total 0, all d become 1 ----
    if (rowtot == 0) {              // block-uniform, rare
        int g = 0;
        for (int i = tid; i < B * T; i += NT) g += dur[i];
        #pragma unroll
        for (int o = 32; o > 0; o >>= 1) g += __shfl_down(g, o);
        __syncthreads();
        if (lane == 0) s_wsum[w] = g;
        __syncthreads();
        int tot = 0;
        #pragma unroll
        for (int i = 0; i < NT / 64; ++i) tot += s_wsum[i];
        if (tot == 0) { d = 1; cum = tid + 1; rowtot = T; }
    }

    const size_t obase = ((size_t)b * TOUT + frame0) * CH;

    // ---- fully-pad window: fill-identical pure-store loop ----
    if (frame0 >= rowtot) {         // block-uniform
        const f4 z = (f4){0.f, 0.f, 0.f, 0.f};
        #pragma unroll
        for (int k = 0; k < ITER; ++k)
            out4[obase + tid + k * NT] = z;
        return;
    }

    // ---- scatter: phoneme tid owns frames [cum-d, cum) ∩ window ----
    if (tid < F) s_idx[tid] = -1;
    __syncthreads();
    {
        int a = cum - d, e = cum;
        if (a < frame0) a = frame0;
        int hi = frame0 + F;
        if (e > hi) e = hi;
        for (int k = a; k < e; ++k) s_idx[k - frame0] = tid;
    }
    __syncthreads();

    // ---- copy: static trip count, contiguous stores, incremental f/c ----
    const size_t ibase = (size_t)b * T * CH;
    int f = tid / CH;               // 0..5 (one div, outside loop)
    int c = tid - f * CH;
    #pragma unroll
    for (int k = 0; k < ITER; ++k) {
        int j = s_idx[f];           // <=2 distinct LDS addrs per wave
        f4 v = (f4){0.f, 0.f, 0.f, 0.f};
        if (j >= 0) v = xs4[ibase + (size_t)j * CH + c];
        out4[obase + tid + k * NT] = v;
        f += NT / CH;               // 512 = 5*96 + 32
        c += NT - (NT / CH) * CH;
        if (c >= CH) { c -= CH; ++f; }   // cndmask under unrolling
    }
}

extern "C" void kernel_launch(void* const* d_in, const int* in_sizes, int n_in,
                              void* d_out, int out_size, void* d_ws, size_t ws_size,
                              hipStream_t stream) {
    const float* xs  = (const float*)d_in[0];
    const int*   dur = (const int*)d_in[1];
    float*       out = (float*)d_out;

    dim3 grid(TOUT / F, B);         // 32 x 32 = 1024 blocks
    k_lenreg<<<grid, NT, 0, stream>>>((const f4*)xs, dur, (f4*)out);
}